// Round 6
// baseline (466.064 us; speedup 1.0000x reference)
//
#include <hip/hip_runtime.h>
#include <hip/hip_bf16.h>

#define N_PTS 65536
#define K_CB  8192
#define D_DIM 64
#define CAPS  63   // candidate slots per row; slot 63 holds the count

typedef float f32x4 __attribute__((ext_vector_type(4)));
typedef short s16x8 __attribute__((ext_vector_type(8)));

__device__ __forceinline__ unsigned bfpack2(float a, float b) {
    union { __hip_bfloat162 h2; unsigned u; } cv;
    cv.h2 = __float22bfloat162_rn(make_float2(a, b));   // RNE pair cvt
    return cv.u;
}

// ---- node 1: e2[K], x2[N] (numpy-pairwise exact) + per-block e2 maxes ----
__global__ __launch_bounds__(256) void vq_prep(
        const float* __restrict__ z, const float* __restrict__ cb,
        float* __restrict__ e2, float* __restrict__ x2, float* __restrict__ bmax) {
#pragma clang fp contract(off)
    __shared__ float sm[4];
    int b = blockIdx.x;
    int lane = threadIdx.x & 63;
    int wv = threadIdx.x >> 6;
    const float* src; float* dst; int row0;
    if (b < 128) { src = cb; dst = e2; row0 = b * 64 + wv * 16; }
    else         { src = z;  dst = x2; row0 = (b - 128) * 64 + wv * 16; }
    float lmax = 0.f;
    for (int r = 0; r < 16; ++r) {
        int row = row0 + r;
        float v = src[(size_t)row * D_DIM + lane];
        float w = v * v;
        float ra = w;
#pragma unroll
        for (int i = 1; i < 8; ++i) ra = ra + __shfl(w, lane + 8 * i, 64);
        float r0 = __shfl(ra, 0, 64), r1 = __shfl(ra, 1, 64),
              r2 = __shfl(ra, 2, 64), r3 = __shfl(ra, 3, 64),
              r4 = __shfl(ra, 4, 64), r5 = __shfl(ra, 5, 64),
              r6 = __shfl(ra, 6, 64), r7 = __shfl(ra, 7, 64);
        if (lane == 0) {
            float s = ((r0 + r1) + (r2 + r3)) + ((r4 + r5) + (r6 + r7));
            dst[row] = s;
            lmax = fmaxf(lmax, s);
        }
    }
    if (b < 128) {
        if (lane == 0) sm[wv] = lmax;
        __syncthreads();
        if (threadIdx.x == 0)
            bmax[b] = fmaxf(fmaxf(sm[0], sm[1]), fmaxf(sm[2], sm[3]));
    }
}

// ---- node 2: pipelined single-sweep coarse argmin ----
// chunk = 128 codes; ping-pong LDS + register prefetch; 1 barrier/chunk.
// bias -e2/2 in MFMA C-init => t = -2*acc; min-t == max-acc.
__global__ __launch_bounds__(256, 3) void vq_coarse(
        const float* __restrict__ z, const float* __restrict__ cb,
        const float* __restrict__ e2, const float* __restrict__ x2,
        const float* __restrict__ bmax, int* __restrict__ cand) {
    __shared__ __align__(16) unsigned short zb[128 * 64];       // 16 KB
    __shared__ __align__(16) unsigned short cbb[2][128 * 64];   // 32 KB
    __shared__ float e2h[2][128];
    __shared__ int cntS[128];

    const int tid = threadIdx.x;
    const int w = tid >> 6, l = tid & 63, tx = l & 15, q = l >> 4;
    const int n0 = blockIdx.x * 128;

    if (tid < 128) cntS[tid] = 0;

    // stage z tile fp32->bf16 once (swizzle proven conflict-free R4/R5)
#pragma unroll
    for (int i = 0; i < 4; ++i) {
        int lin = tid + 256 * i;
        int row = lin >> 3, u = lin & 7;
        const float4* p = (const float4*)(z + (size_t)(n0 + row) * D_DIM + u * 8);
        float4 a = p[0], b2 = p[1];
        uint4 pk;
        pk.x = bfpack2(a.x, a.y);   pk.y = bfpack2(a.z, a.w);
        pk.z = bfpack2(b2.x, b2.y); pk.w = bfpack2(b2.z, b2.w);
        *(uint4*)&zb[row * 64 + ((u ^ (row & 7)) * 8)] = pk;
    }
    // stage chunk 0 into buffer 0
#pragma unroll
    for (int i = 0; i < 4; ++i) {
        int lin = tid + 256 * i;
        int row = lin >> 3, u = lin & 7;
        const float4* p = (const float4*)(cb + (size_t)row * D_DIM + u * 8);
        float4 a = p[0], b2 = p[1];
        uint4 pk;
        pk.x = bfpack2(a.x, a.y);   pk.y = bfpack2(a.z, a.w);
        pk.z = bfpack2(b2.x, b2.y); pk.w = bfpack2(b2.z, b2.w);
        *(uint4*)&cbb[0][row * 64 + ((u ^ (row & 7)) * 8)] = pk;
    }
    if (tid < 128) e2h[0][tid] = e2[tid];

    float e2m;   // global e2max from prep's per-block maxes
    {
        float v = fmaxf(bmax[l], bmax[l + 64]);
#pragma unroll
        for (int m = 1; m < 64; m <<= 1) v = fmaxf(v, __shfl_xor(v, m, 64));
        e2m = v;
    }

    float halfW[8], A[8], M[8];
#pragma unroll
    for (int i = 0; i < 8; ++i) {
        int row = n0 + w * 32 + (i >> 2) * 16 + q * 4 + (i & 3);
        halfW[i] = 0.0175f * sqrtf(x2[row] * e2m) + 1e-4f;   // R4/R5-proven window
        A[i] = 3.0e38f;      // suppresses collection until first threshold update
        M[i] = -3.4e38f;
    }

    s16x8 afr[2][2];
    float4 pfa[4], pfb[4];
    float  e2p = 0.f;

    for (int it = 0; it < 66; ++it) {        // 64 chunks + revisit chunks 0,1
        const int buf = it & 1;
        const int kc  = (it < 64) ? it : (it - 64);

        __syncthreads();   // write(it-1)->read(it) AND read(it-1)->write(it)

        if (it == 0) {     // A-frags register-resident for the whole kernel
#pragma unroll
            for (int rt = 0; rt < 2; ++rt)
#pragma unroll
                for (int ks = 0; ks < 2; ++ks) {
                    int row = w * 32 + rt * 16 + tx;
                    afr[rt][ks] = *(const s16x8*)&zb[row * 64 + (((ks * 4 + q) ^ (tx & 7)) * 8)];
                }
        }

        // issue next-chunk prefetch NOW; vmcnt waited only at the ds_write below
        const int itn = it + 1;
        const bool hav = (itn < 66);
        if (hav) {
            const int kcn = (itn < 64) ? itn : (itn - 64);
            const float* src = cb + (size_t)kcn * 128 * D_DIM;
#pragma unroll
            for (int i = 0; i < 4; ++i) {
                int lin = tid + 256 * i;
                int row = lin >> 3, u = lin & 7;
                const float4* p = (const float4*)(src + (size_t)row * D_DIM + u * 8);
                pfa[i] = p[0]; pfb[i] = p[1];
            }
            if (tid < 128) e2p = e2[kcn * 128 + tid];
        }

        // ---- compute current chunk ----
#pragma unroll
        for (int ct = 0; ct < 8; ++ct) {
            const int crow = ct * 16 + tx;
            const float bias = -0.5f * e2h[buf][crow];
            const s16x8 b0 = *(const s16x8*)&cbb[buf][crow * 64 + ((q ^ (tx & 7)) * 8)];
            const s16x8 b1 = *(const s16x8*)&cbb[buf][crow * 64 + (((4 + q) ^ (tx & 7)) * 8)];
            const int kglob = kc * 128 + crow;
#pragma unroll
            for (int rt = 0; rt < 2; ++rt) {
                f32x4 acc = {bias, bias, bias, bias};
                acc = __builtin_amdgcn_mfma_f32_16x16x32_bf16(afr[rt][0], b0, acc, 0, 0, 0);
                acc = __builtin_amdgcn_mfma_f32_16x16x32_bf16(afr[rt][1], b1, acc, 0, 0, 0);
                bool h0 = acc[0] >= A[rt * 4 + 0];
                bool h1 = acc[1] >= A[rt * 4 + 1];
                bool h2 = acc[2] >= A[rt * 4 + 2];
                bool h3 = acc[3] >= A[rt * 4 + 3];
                M[rt * 4 + 0] = fmaxf(M[rt * 4 + 0], acc[0]);
                M[rt * 4 + 1] = fmaxf(M[rt * 4 + 1], acc[1]);
                M[rt * 4 + 2] = fmaxf(M[rt * 4 + 2], acc[2]);
                M[rt * 4 + 3] = fmaxf(M[rt * 4 + 3], acc[3]);
                if (__builtin_expect(h0 | h1 | h2 | h3, 0)) {   // one rare branch per rt
#pragma unroll
                    for (int r = 0; r < 4; ++r)
                        if (acc[r] >= A[rt * 4 + r]) {
                            int rowL = w * 32 + rt * 16 + q * 4 + r;
                            int slot = atomicAdd(&cntS[rowL], 1);
                            if (slot < CAPS)
                                cand[(size_t)(n0 + rowL) * 64 + slot] = kglob;
                        }
                }
            }
        }

        if ((it & 1) == 1 && it < 64) {   // threshold update every 2 chunks
#pragma unroll
            for (int i = 0; i < 8; ++i) {
                float v = M[i];
                v = fmaxf(v, __shfl_xor(v, 1, 64));
                v = fmaxf(v, __shfl_xor(v, 2, 64));
                v = fmaxf(v, __shfl_xor(v, 4, 64));
                v = fmaxf(v, __shfl_xor(v, 8, 64));
                M[i] = v;
                A[i] = v - halfW[i];
            }
        }

        // ---- write prefetched chunk into the other buffer ----
        if (hav) {
            const int nb = buf ^ 1;
#pragma unroll
            for (int i = 0; i < 4; ++i) {
                int lin = tid + 256 * i;
                int row = lin >> 3, u = lin & 7;
                uint4 pk;
                pk.x = bfpack2(pfa[i].x, pfa[i].y); pk.y = bfpack2(pfa[i].z, pfa[i].w);
                pk.z = bfpack2(pfb[i].x, pfb[i].y); pk.w = bfpack2(pfb[i].z, pfb[i].w);
                *(uint4*)&cbb[nb][row * 64 + ((u ^ (row & 7)) * 8)] = pk;
            }
            if (tid < 128) e2h[nb][tid] = e2p;
        }
    }
    __syncthreads();
    if (tid < 128) cand[(size_t)(n0 + tid) * 64 + 63] = cntS[tid];
}

// ---- exact fp32 rescore: bit-identical to the round-3/4/5 passing pipeline ----
__device__ __forceinline__ float exact_score(const float* zr, const float* __restrict__ cb,
                                             const float* __restrict__ e2, float x2v, int k) {
    const float4* c4 = (const float4*)(cb + (size_t)k * D_DIM);
    float g = 0.f;
#pragma unroll
    for (int j = 0; j < 16; ++j) {
        float4 v = c4[j];
        g = fmaf(zr[4 * j + 0], v.x, g);
        g = fmaf(zr[4 * j + 1], v.y, g);
        g = fmaf(zr[4 * j + 2], v.z, g);
        g = fmaf(zr[4 * j + 3], v.w, g);
    }
    return fmaf(-2.f, g, x2v) + e2[k];
}

// ---- node 3: rescore + gather + straight-through write + loss partials ----
__global__ __launch_bounds__(256, 2) void vq_rescore(
        const float* __restrict__ z, const float* __restrict__ cb,
        const float* __restrict__ e2, const float* __restrict__ x2,
        int* __restrict__ slots, float* __restrict__ idx_out,
        float* __restrict__ partials) {
    int tid = threadIdx.x;
    int n = blockIdx.x * 256 + tid;
    float zr[64];
    const float4* z4 = (const float4*)(z + (size_t)n * D_DIM);
#pragma unroll
    for (int i = 0; i < 16; ++i) {
        float4 v = z4[i];
        zr[4 * i] = v.x; zr[4 * i + 1] = v.y; zr[4 * i + 2] = v.z; zr[4 * i + 3] = v.w;
    }
    float x2v = x2[n];
    int cnt = slots[(size_t)n * 64 + 63];
    float bs = 3.4e38f; int bk = 0x7fffffff;
    if (cnt <= CAPS) {
        for (int i = 0; i < cnt; ++i) {
            int k = slots[(size_t)n * 64 + i];
            float s = exact_score(zr, cb, e2, x2v, k);
            if (s < bs || (s == bs && k < bk)) { bs = s; bk = k; }
        }
    }
    // wave-cooperative full scan for overflowed rows (~never taken)
    unsigned long long mask = __ballot(cnt > CAPS);
    while (mask) {
        int src = __ffsll((long long)mask) - 1;
        mask &= (mask - 1);
        int rown = __shfl(n, src, 64);
        float x2s = __shfl(x2v, src, 64);
        float zs[64];
        const float4* zz = (const float4*)(z + (size_t)rown * D_DIM);
#pragma unroll
        for (int i = 0; i < 16; ++i) {
            float4 v = zz[i];
            zs[4 * i] = v.x; zs[4 * i + 1] = v.y; zs[4 * i + 2] = v.z; zs[4 * i + 3] = v.w;
        }
        float fb = 3.4e38f; int fk = 0x7fffffff;
        for (int k = (tid & 63); k < K_CB; k += 64) {
            float s = exact_score(zs, cb, e2, x2s, k);
            if (s < fb || (s == fb && k < fk)) { fb = s; fk = k; }
        }
#pragma unroll
        for (int m = 1; m < 64; m <<= 1) {
            float ov = __shfl_xor(fb, m, 64);
            int   ok = __shfl_xor(fk, m, 64);
            if (ov < fb || (ov == fb && ok < fk)) { fb = ov; fk = ok; }
        }
        if ((tid & 63) == src) { bs = fb; bk = fk; }
    }
    idx_out[n] = (float)bk;
    __threadfence_block();   // slot reads drained before aliased zq writes

    float lsum = 0.f;
    const float4* c4 = (const float4*)(cb + (size_t)bk * D_DIM);
    float4* o4 = (float4*)((float*)slots + (size_t)n * 64);
#pragma unroll
    for (int j = 0; j < 16; ++j) {
        float4 c = c4[j];
        float4 o;
        float d0 = c.x - zr[4 * j];     o.x = zr[4 * j]     + d0;
        float d1 = c.y - zr[4 * j + 1]; o.y = zr[4 * j + 1] + d1;
        float d2 = c.z - zr[4 * j + 2]; o.z = zr[4 * j + 2] + d2;
        float d3 = c.w - zr[4 * j + 3]; o.w = zr[4 * j + 3] + d3;
        lsum += d0 * d0 + d1 * d1 + d2 * d2 + d3 * d3;
        o4[j] = o;
    }
    __shared__ float red[256];
    red[tid] = lsum;
    __syncthreads();
    for (int s = 128; s > 0; s >>= 1) {
        if (tid < s) red[tid] += red[tid + s];
        __syncthreads();
    }
    if (tid == 0) partials[blockIdx.x] = red[0];
}

// ---- node 4: final loss ----
__global__ void vq_final(const float* __restrict__ partials, float* __restrict__ loss_out) {
    __shared__ float red[256];
    int tid = threadIdx.x;
    red[tid] = partials[tid];
    __syncthreads();
    for (int s = 128; s > 0; s >>= 1) {
        if (tid < s) red[tid] += red[tid + s];
        __syncthreads();
    }
    if (tid == 0) *loss_out = 1.25f * red[0] / (float)(N_PTS * D_DIM);
}

extern "C" void kernel_launch(void* const* d_in, const int* in_sizes, int n_in,
                              void* d_out, int out_size, void* d_ws, size_t ws_size,
                              hipStream_t stream) {
    const float* z  = (const float*)d_in[0];
    const float* cb = (const float*)d_in[1];
    float* out      = (float*)d_out;
    float* zq_out   = out;                          // [N*64]; doubles as cand slots
    float* loss_out = out + (size_t)N_PTS * D_DIM;  // [1]
    float* idx_out  = loss_out + 1;                 // [N]; [0..127] doubles as bmax scratch

    float* wsf = (float*)d_ws;
    float* partials = wsf;                          // 256 floats (always fully written)
    float* e2 = wsf + 256;                          // K floats
    float* x2 = wsf + 256 + K_CB;                   // N floats

    int* cand = (int*)zq_out;
    float* bmax = idx_out;                          // overwritten by rescore afterwards

    vq_prep   <<<128 + N_PTS / 64, 256, 0, stream>>>(z, cb, e2, x2, bmax);
    vq_coarse <<<N_PTS / 128, 256, 0, stream>>>(z, cb, e2, x2, bmax, cand);
    vq_rescore<<<N_PTS / 256, 256, 0, stream>>>(z, cb, e2, x2, cand, idx_out, partials);
    vq_final  <<<1, 256, 0, stream>>>(partials, loss_out);
}